// Round 1
// baseline (5885.566 us; speedup 1.0000x reference)
//
#include <hip/hip_runtime.h>
#include <math.h>

#define BB 8
#define LL 196
#define DD 384
#define NDEPTH 24
#define NST 16
#define RRANK 24
#define HHID 1024
#define MROWS (BB*LL)   /* 1568 */
#define NCH 14          /* chunks */
#define CHL 14          /* chunk length: 14*14 = 196 */

__device__ __forceinline__ float sigmoidf_(float x){ return 1.f/(1.f+__expf(-x)); }

// ---------------- LayerNorm (row per block, 64 threads) ----------------
__global__ __launch_bounds__(64) void ln_k(const float* __restrict__ X,
    const float* __restrict__ w, const float* __restrict__ b,
    float* __restrict__ Y)
{
    int row = blockIdx.x;
    int lane = threadIdx.x;
    const float* x = X + (size_t)row*DD;
    float v[6]; float s=0.f, s2=0.f;
    #pragma unroll
    for (int j=0;j<6;j++){ float t = x[lane + j*64]; v[j]=t; s+=t; s2+=t*t; }
    #pragma unroll
    for (int o=32;o>=1;o>>=1){ s += __shfl_xor(s,o); s2 += __shfl_xor(s2,o); }
    float m = s*(1.f/DD);
    float var = s2*(1.f/DD) - m*m;
    float rstd = rsqrtf(var + 1e-5f);
    float* y = Y + (size_t)row*DD;
    #pragma unroll
    for (int j=0;j<6;j++){
        int c = lane + j*64;
        y[c] = (v[j]-m)*rstd*w[c] + b[c];
    }
}

// ---------------- Patch gather: x (B,3,224,224) -> P (B*L, 768) ----------------
__global__ void gather_k(const float* __restrict__ x, float* __restrict__ P)
{
    int idx = blockIdx.x*blockDim.x + threadIdx.x;
    if (idx >= MROWS*768) return;
    int k = idx % 768;
    int bl = idx / 768;
    int l = bl % LL;
    int b = bl / LL;
    int c = k >> 8;
    int rem = k & 255;
    int dy = rem >> 4, dx = rem & 15;
    int py = l / 14, px = l % 14;
    P[idx] = x[(((size_t)b*3 + c)*224 + (py*16+dy))*224 + (px*16+dx)];
}

// ---------------- Causal depthwise conv (K=4) + SiLU ----------------
__global__ void conv_silu_k(const float* __restrict__ xz,
    const float* __restrict__ cw, const float* __restrict__ cb,
    float* __restrict__ xa)
{
    int idx = blockIdx.x*blockDim.x + threadIdx.x;
    if (idx >= MROWS*DD) return;
    int d = idx % DD;
    int bl = idx / DD;
    int l = bl % LL;
    int b = bl / LL;
    float acc = cb[d];
    #pragma unroll
    for (int k=0;k<4;k++){
        int ls = l + k - 3;
        if (ls >= 0) acc = fmaf(xz[(size_t)(b*LL+ls)*768 + d], cw[d*4+k], acc);
    }
    xa[idx] = acc * sigmoidf_(acc);
}

// ---------------- Generic tiled GEMM: C(M,N) = A(M,K;lda) * W(N,K)^T ----------------
// EPI: 0 plain | 1 +bias | 2 +C(residual) | 3 +C+bias | 4 silu(acc1+b1)*(acc2+b2) | 5 softplus(acc+bias)
template<int EPI>
__global__ __launch_bounds__(256) void gemm_k(
    const float* __restrict__ A, int lda,
    const float* __restrict__ W,
    const float* __restrict__ bias,
    const float* __restrict__ W2,
    const float* __restrict__ bias2,
    float* __restrict__ C,
    int M, int N, int K)
{
    __shared__ float As[16][68];
    __shared__ float Ws1[16][68];
    __shared__ float Ws2[(EPI==4)?16:1][68];

    int tid = threadIdx.x;
    int tx = tid & 15, ty = tid >> 4;
    int row0 = blockIdx.y*64, col0 = blockIdx.x*64;

    int ldr  = tid >> 2;
    int ldk4 = (tid & 3) << 2;

    float acc[4][4] = {{0.f}};
    float acc2[4][4] = {{0.f}};

    const float* Arow  = A + (size_t)(row0+ldr)*lda;
    const float* Wrow  = W + (size_t)(col0+ldr)*K;
    const float* W2row = (EPI==4) ? (W2 + (size_t)(col0+ldr)*K) : nullptr;
    bool aok = (row0+ldr) < M;
    bool wok = (col0+ldr) < N;

    int KT = (K+15) >> 4;
    for (int kt=0; kt<KT; kt++){
        int kg = kt*16 + ldk4;
        float4 av = {0,0,0,0}, wv = {0,0,0,0}, w2v = {0,0,0,0};
        if (aok){
            if (kg+4 <= K) av = *(const float4*)(Arow + kg);
            else {
                if (kg   < K) av.x = Arow[kg];
                if (kg+1 < K) av.y = Arow[kg+1];
                if (kg+2 < K) av.z = Arow[kg+2];
                if (kg+3 < K) av.w = Arow[kg+3];
            }
        }
        if (wok){
            if (kg+4 <= K) wv = *(const float4*)(Wrow + kg);
            else {
                if (kg   < K) wv.x = Wrow[kg];
                if (kg+1 < K) wv.y = Wrow[kg+1];
                if (kg+2 < K) wv.z = Wrow[kg+2];
                if (kg+3 < K) wv.w = Wrow[kg+3];
            }
        }
        if (EPI==4 && wok){
            if (kg+4 <= K) w2v = *(const float4*)(W2row + kg);
            else {
                if (kg   < K) w2v.x = W2row[kg];
                if (kg+1 < K) w2v.y = W2row[kg+1];
                if (kg+2 < K) w2v.z = W2row[kg+2];
                if (kg+3 < K) w2v.w = W2row[kg+3];
            }
        }
        __syncthreads();
        As [ldk4+0][ldr]=av.x; As [ldk4+1][ldr]=av.y; As [ldk4+2][ldr]=av.z; As [ldk4+3][ldr]=av.w;
        Ws1[ldk4+0][ldr]=wv.x; Ws1[ldk4+1][ldr]=wv.y; Ws1[ldk4+2][ldr]=wv.z; Ws1[ldk4+3][ldr]=wv.w;
        if (EPI==4){
            Ws2[ldk4+0][ldr]=w2v.x; Ws2[ldk4+1][ldr]=w2v.y; Ws2[ldk4+2][ldr]=w2v.z; Ws2[ldk4+3][ldr]=w2v.w;
        }
        __syncthreads();
        #pragma unroll
        for (int k=0;k<16;k++){
            const float4 a  = *(const float4*)&As[k][ty<<2];
            const float4 b1 = *(const float4*)&Ws1[k][tx<<2];
            float ar[4] = {a.x,a.y,a.z,a.w};
            float br[4] = {b1.x,b1.y,b1.z,b1.w};
            #pragma unroll
            for (int i=0;i<4;i++)
                #pragma unroll
                for (int j=0;j<4;j++)
                    acc[i][j] = fmaf(ar[i], br[j], acc[i][j]);
            if (EPI==4){
                const float4 b2 = *(const float4*)&Ws2[k][tx<<2];
                float c2[4] = {b2.x,b2.y,b2.z,b2.w};
                #pragma unroll
                for (int i=0;i<4;i++)
                    #pragma unroll
                    for (int j=0;j<4;j++)
                        acc2[i][j] = fmaf(ar[i], c2[j], acc2[i][j]);
            }
        }
    }

    int c0 = col0 + (tx<<2);
    if (c0 >= N) return;
    bool full = (c0+4 <= N);
    float bb1[4] = {0,0,0,0}, bb2[4] = {0,0,0,0};
    if (EPI==1||EPI==3||EPI==4||EPI==5){
        if (full){ float4 bz = *(const float4*)&bias[c0]; bb1[0]=bz.x; bb1[1]=bz.y; bb1[2]=bz.z; bb1[3]=bz.w; }
        else { for (int j=0;j<4;j++) if (c0+j<N) bb1[j]=bias[c0+j]; }
    }
    if (EPI==4){
        if (full){ float4 bz = *(const float4*)&bias2[c0]; bb2[0]=bz.x; bb2[1]=bz.y; bb2[2]=bz.z; bb2[3]=bz.w; }
        else { for (int j=0;j<4;j++) if (c0+j<N) bb2[j]=bias2[c0+j]; }
    }
    #pragma unroll
    for (int i=0;i<4;i++){
        int r = row0 + (ty<<2) + i;
        if (r >= M) continue;
        float o[4];
        #pragma unroll
        for (int j=0;j<4;j++){
            float v = acc[i][j];
            if (EPI==1||EPI==3) v += bb1[j];
            if (EPI==5){ float t = v + bb1[j]; v = (t > 20.f) ? t : log1pf(__expf(t)); }
            if (EPI==4){
                float v1 = v + bb1[j];
                float v2 = acc2[i][j] + bb2[j];
                v = v1 * sigmoidf_(v1) * v2;
            }
            o[j] = v;
        }
        size_t off = (size_t)r*N + c0;
        if (EPI==2||EPI==3){
            if (full){ float4 cv = *(const float4*)&C[off]; o[0]+=cv.x; o[1]+=cv.y; o[2]+=cv.z; o[3]+=cv.w; }
            else { for (int j=0;j<4;j++) if (c0+j<N) o[j]+=C[off+j]; }
        }
        if (full){ float4 ov = {o[0],o[1],o[2],o[3]}; *(float4*)&C[off] = ov; }
        else { for (int j=0;j<4;j++) if (c0+j<N) C[off+j]=o[j]; }
    }
}

// ---------------- Scan phase A: per-chunk local scan -> P (decay prod), S (local state) ----------------
__global__ __launch_bounds__(384) void scanA_k(
    const float* __restrict__ dt, const float* __restrict__ xa,
    const float* __restrict__ dbc, const float* __restrict__ a_log,
    float* __restrict__ Pout, float* __restrict__ Sout)
{
    int b = blockIdx.x / NCH;
    int c = blockIdx.x % NCH;
    int d = threadIdx.x;
    __shared__ float Bs[CHL][NST];
    for (int t = threadIdx.x; t < CHL*NST; t += 384){
        int j = t >> 4, n = t & 15;
        Bs[j][n] = dbc[(size_t)(b*LL + c*CHL + j)*56 + 24 + n];
    }
    __syncthreads();
    float Aa[NST];
    #pragma unroll
    for (int n=0;n<NST;n++) Aa[n] = -__expf(a_log[d*NST+n]);
    float hst[NST], P[NST];
    #pragma unroll
    for (int n=0;n<NST;n++){ hst[n]=0.f; P[n]=1.f; }
    for (int j=0;j<CHL;j++){
        int row = b*LL + c*CHL + j;
        float dtv = dt[(size_t)row*DD + d];
        float xv  = xa[(size_t)row*DD + d];
        float du = dtv*xv;
        #pragma unroll
        for (int n=0;n<NST;n++){
            float e = __expf(dtv*Aa[n]);
            hst[n] = fmaf(hst[n], e, du*Bs[j][n]);
            P[n] *= e;
        }
    }
    size_t base = ((size_t)(b*NCH + c)*DD + d)*NST;
    #pragma unroll
    for (int n=0;n<NST;n++){ Pout[base+n]=P[n]; Sout[base+n]=hst[n]; }
}

// ---------------- Scan phase B: sequential chunk combine, store per-chunk initial state ----------------
__global__ void scanB_k(const float* __restrict__ P, const float* __restrict__ S,
                        float* __restrict__ Hin)
{
    int idx = blockIdx.x*blockDim.x + threadIdx.x;
    if (idx >= BB*DD) return;
    int b = idx / DD, d = idx % DD;
    float h[NST];
    #pragma unroll
    for (int n=0;n<NST;n++) h[n]=0.f;
    for (int c=0;c<NCH;c++){
        size_t base = ((size_t)(b*NCH + c)*DD + d)*NST;
        #pragma unroll
        for (int n=0;n<NST;n++){
            Hin[base+n] = h[n];
            h[n] = fmaf(P[base+n], h[n], S[base+n]);
        }
    }
}

// ---------------- Scan phase C: replay with correct h0, emit gated y ----------------
__global__ __launch_bounds__(384) void scanC_k(
    const float* __restrict__ dt, const float* __restrict__ xa,
    const float* __restrict__ dbc, const float* __restrict__ a_log,
    const float* __restrict__ Hin, const float* __restrict__ xz,
    const float* __restrict__ dskip, float* __restrict__ yg)
{
    int b = blockIdx.x / NCH;
    int c = blockIdx.x % NCH;
    int d = threadIdx.x;
    __shared__ float Bs[CHL][NST], Cs[CHL][NST];
    for (int t = threadIdx.x; t < CHL*NST*2; t += 384){
        int which = t / (CHL*NST);
        int u = t % (CHL*NST);
        int j = u >> 4, n = u & 15;
        float v = dbc[(size_t)(b*LL + c*CHL + j)*56 + 24 + which*NST + n];
        if (which==0) Bs[j][n]=v; else Cs[j][n]=v;
    }
    __syncthreads();
    float Aa[NST];
    #pragma unroll
    for (int n=0;n<NST;n++) Aa[n] = -__expf(a_log[d*NST+n]);
    float hst[NST];
    size_t hb = ((size_t)(b*NCH + c)*DD + d)*NST;
    #pragma unroll
    for (int n=0;n<NST;n++) hst[n] = Hin[hb+n];
    float dsk = dskip[d];
    for (int j=0;j<CHL;j++){
        int row = b*LL + c*CHL + j;
        float dtv = dt[(size_t)row*DD + d];
        float xv  = xa[(size_t)row*DD + d];
        float du = dtv*xv;
        float y = 0.f;
        #pragma unroll
        for (int n=0;n<NST;n++){
            float e = __expf(dtv*Aa[n]);
            hst[n] = fmaf(hst[n], e, du*Bs[j][n]);
            y = fmaf(hst[n], Cs[j][n], y);
        }
        float zv = xz[(size_t)row*768 + 384 + d];
        float g = zv * sigmoidf_(zv);
        yg[(size_t)row*DD + d] = (y + dsk*xv)*g;
    }
}

extern "C" void kernel_launch(void* const* d_in, const int* in_sizes, int n_in,
                              void* d_out, int out_size, void* d_ws, size_t ws_size,
                              hipStream_t stream)
{
    const float* x         = (const float*)d_in[0];
    const float* patch_w   = (const float*)d_in[1];
    const float* patch_b   = (const float*)d_in[2];
    const float* norm1_w   = (const float*)d_in[3];
    const float* norm1_b   = (const float*)d_in[4];
    const float* in_proj_w = (const float*)d_in[5];
    const float* conv_w    = (const float*)d_in[6];
    const float* conv_b    = (const float*)d_in[7];
    const float* x_proj_w  = (const float*)d_in[8];
    const float* dt_w      = (const float*)d_in[9];
    const float* dt_b      = (const float*)d_in[10];
    const float* A_log     = (const float*)d_in[11];
    const float* D_skip    = (const float*)d_in[12];
    const float* out_w     = (const float*)d_in[13];
    const float* norm2_w   = (const float*)d_in[14];
    const float* norm2_b   = (const float*)d_in[15];
    const float* w1_w      = (const float*)d_in[16];
    const float* w1_b      = (const float*)d_in[17];
    const float* w2_w      = (const float*)d_in[18];
    const float* w2_b      = (const float*)d_in[19];
    const float* w3_w      = (const float*)d_in[20];
    const float* w3_b      = (const float*)d_in[21];
    const float* normf_w   = (const float*)d_in[22];
    const float* normf_b   = (const float*)d_in[23];

    float* ws   = (float*)d_ws;
    float* h    = ws;                    // 602112
    float* xn   = h    + 602112;         // 602112
    float* xz   = xn   + 602112;         // 1204224
    float* xa   = xz   + 1204224;        // 602112
    float* dbc  = xa   + 602112;         // 87808
    float* dtb_ = dbc  + 87808;          // 602112
    float* yg   = dtb_ + 602112;         // 602112
    float* hid  = yg   + 602112;         // 1605632  (also reused as patches buffer)
    float* Pbuf = hid  + 1605632;        // 688128
    float* Sbuf = Pbuf + 688128;         // 688128
    float* Hin  = Sbuf + 688128;         // 688128
    float* patches = hid;                // reuse: patches (1204224) consumed before hid is produced

    dim3 blk(256);

    // Patch embedding
    gather_k<<<(MROWS*768+255)/256, 256, 0, stream>>>(x, patches);
    gemm_k<1><<<dim3(6,25), blk, 0, stream>>>(patches, 768, patch_w, patch_b,
                                              nullptr, nullptr, h, MROWS, DD, 768);

    for (int i=0;i<NDEPTH;i++){
        ln_k<<<MROWS, 64, 0, stream>>>(h, norm1_w + i*DD, norm1_b + i*DD, xn);
        gemm_k<0><<<dim3(12,25), blk, 0, stream>>>(xn, DD, in_proj_w + (size_t)i*768*DD,
                                                   nullptr, nullptr, nullptr, xz, MROWS, 768, DD);
        conv_silu_k<<<(MROWS*DD+255)/256, 256, 0, stream>>>(xz, conv_w + i*DD*4, conv_b + i*DD, xa);
        gemm_k<0><<<dim3(1,25), blk, 0, stream>>>(xa, DD, x_proj_w + (size_t)i*56*DD,
                                                  nullptr, nullptr, nullptr, dbc, MROWS, 56, DD);
        gemm_k<5><<<dim3(6,25), blk, 0, stream>>>(dbc, 56, dt_w + (size_t)i*DD*RRANK, dt_b + i*DD,
                                                  nullptr, nullptr, dtb_, MROWS, DD, RRANK);
        scanA_k<<<BB*NCH, DD, 0, stream>>>(dtb_, xa, dbc, A_log + (size_t)i*DD*NST, Pbuf, Sbuf);
        scanB_k<<<(BB*DD+255)/256, 256, 0, stream>>>(Pbuf, Sbuf, Hin);
        scanC_k<<<BB*NCH, DD, 0, stream>>>(dtb_, xa, dbc, A_log + (size_t)i*DD*NST,
                                           Hin, xz, D_skip + i*DD, yg);
        gemm_k<2><<<dim3(6,25), blk, 0, stream>>>(yg, DD, out_w + (size_t)i*DD*DD,
                                                  nullptr, nullptr, nullptr, h, MROWS, DD, DD);
        ln_k<<<MROWS, 64, 0, stream>>>(h, norm2_w + i*DD, norm2_b + i*DD, xn);
        gemm_k<4><<<dim3(16,25), blk, 0, stream>>>(xn, DD, w1_w + (size_t)i*HHID*DD, w1_b + i*HHID,
                                                   w2_w + (size_t)i*HHID*DD, w2_b + i*HHID,
                                                   hid, MROWS, HHID, DD);
        gemm_k<3><<<dim3(6,25), blk, 0, stream>>>(hid, HHID, w3_w + (size_t)i*DD*HHID, w3_b + i*DD,
                                                  nullptr, nullptr, h, MROWS, DD, HHID);
    }

    ln_k<<<MROWS, 64, 0, stream>>>(h, normf_w, normf_b, (float*)d_out);
}

// Round 2
// 3426.037 us; speedup vs baseline: 1.7179x; 1.7179x over previous
//
#include <hip/hip_runtime.h>
#include <math.h>

#define BB 8
#define LL 196
#define DD 384
#define NDEPTH 24
#define NST 16
#define RRANK 24
#define HHID 1024
#define MROWS (BB*LL)   /* 1568 */
#define NCH 14
#define CHL 14

typedef float f32x4 __attribute__((ext_vector_type(4)));
typedef short s16x8 __attribute__((ext_vector_type(8)));
typedef short s16x4 __attribute__((ext_vector_type(4)));
typedef __bf16 b16x8 __attribute__((ext_vector_type(8)));
typedef unsigned short u16;
typedef unsigned int u32;

__device__ __forceinline__ float sigmoidf_(float x){ return 1.f/(1.f+__expf(-x)); }

__device__ __forceinline__ u16 f2bf(float f){
    u32 u = __builtin_bit_cast(u32, f);
    u32 r = (u + 0x7fffu + ((u >> 16) & 1u)) >> 16;   // RNE
    return (u16)r;
}

// ---- MFMA wrapper: SFINAE hedge over builtin operand type (short8 vs __bf16 x8) ----
template<typename V>
__device__ __forceinline__ auto mfma_try(V a, V b, f32x4 c, int)
    -> decltype(__builtin_amdgcn_mfma_f32_16x16x32_bf16(a, b, c, 0, 0, 0))
{ return __builtin_amdgcn_mfma_f32_16x16x32_bf16(a, b, c, 0, 0, 0); }

template<typename V>
__device__ __forceinline__ f32x4 mfma_try(V a, V b, f32x4 c, long)
{
    return __builtin_amdgcn_mfma_f32_16x16x32_bf16(
        __builtin_bit_cast(b16x8, a), __builtin_bit_cast(b16x8, b), c, 0, 0, 0);
}
__device__ __forceinline__ f32x4 mfma_bf16(s16x8 a, s16x8 b, f32x4 c){ return mfma_try(a, b, c, 0); }

// ---------------- LayerNorm: BF=1 -> bf16 out, BF=0 -> f32 out ----------------
template<int BF>
__global__ __launch_bounds__(64) void ln_k(const float* __restrict__ X,
    const float* __restrict__ w, const float* __restrict__ b, void* __restrict__ Yv)
{
    int row = blockIdx.x;
    int lane = threadIdx.x;
    const float* x = X + (size_t)row*DD;
    float v[6]; float s=0.f, s2=0.f;
    #pragma unroll
    for (int j=0;j<6;j++){ float t = x[lane + j*64]; v[j]=t; s+=t; s2+=t*t; }
    #pragma unroll
    for (int o=32;o>=1;o>>=1){ s += __shfl_xor(s,o); s2 += __shfl_xor(s2,o); }
    float m = s*(1.f/DD);
    float var = s2*(1.f/DD) - m*m;
    float rstd = rsqrtf(var + 1e-5f);
    #pragma unroll
    for (int j=0;j<6;j++){
        int c = lane + j*64;
        float val = (v[j]-m)*rstd*w[c] + b[c];
        if (BF) ((u16*)Yv)[(size_t)row*DD + c] = f2bf(val);
        else    ((float*)Yv)[(size_t)row*DD + c] = val;
    }
}

// ---------------- Patch gather -> bf16 (B*L, 768) ----------------
__global__ void gather_k(const float* __restrict__ x, u16* __restrict__ P)
{
    int idx = blockIdx.x*blockDim.x + threadIdx.x;
    if (idx >= MROWS*768) return;
    int k = idx % 768;
    int bl = idx / 768;
    int l = bl % LL;
    int b = bl / LL;
    int c = k >> 8;
    int rem = k & 255;
    int dy = rem >> 4, dx = rem & 15;
    int py = l / 14, px = l % 14;
    P[idx] = f2bf(x[(((size_t)b*3 + c)*224 + (py*16+dy))*224 + (px*16+dx)]);
}

// ---------------- Causal depthwise conv (K=4) + SiLU ----------------
__global__ void conv_silu_k(const float* __restrict__ xz,
    const float* __restrict__ cw, const float* __restrict__ cb,
    float* __restrict__ xa)
{
    int idx = blockIdx.x*blockDim.x + threadIdx.x;
    if (idx >= MROWS*DD) return;
    int d = idx % DD;
    int bl = idx / DD;
    int l = bl % LL;
    int b = bl / LL;
    float acc = cb[d];
    #pragma unroll
    for (int k=0;k<4;k++){
        int ls = l + k - 3;
        if (ls >= 0) acc = fmaf(xz[(size_t)(b*LL+ls)*768 + d], cw[d*4+k], acc);
    }
    xa[idx] = acc * sigmoidf_(acc);
}

// ---------------- small fp32 GEMM (x_proj, dt_proj): C(M,N)=A(M,K;lda)*W(N,K)^T ----------------
// EPI: 0 plain | 5 softplus(acc+bias)
template<int EPI>
__global__ __launch_bounds__(256) void gemm_k(
    const float* __restrict__ A, int lda,
    const float* __restrict__ W,
    const float* __restrict__ bias,
    float* __restrict__ C,
    int M, int N, int K)
{
    __shared__ float As[16][68];
    __shared__ float Ws1[16][68];

    int tid = threadIdx.x;
    int tx = tid & 15, ty = tid >> 4;
    int row0 = blockIdx.y*64, col0 = blockIdx.x*64;

    int ldr  = tid >> 2;
    int ldk4 = (tid & 3) << 2;

    float acc[4][4] = {{0.f}};

    const float* Arow  = A + (size_t)(row0+ldr)*lda;
    const float* Wrow  = W + (size_t)(col0+ldr)*K;
    bool aok = (row0+ldr) < M;
    bool wok = (col0+ldr) < N;

    int KT = (K+15) >> 4;
    for (int kt=0; kt<KT; kt++){
        int kg = kt*16 + ldk4;
        float4 av = {0,0,0,0}, wv = {0,0,0,0};
        if (aok){
            if (kg+4 <= K) av = *(const float4*)(Arow + kg);
            else {
                if (kg   < K) av.x = Arow[kg];
                if (kg+1 < K) av.y = Arow[kg+1];
                if (kg+2 < K) av.z = Arow[kg+2];
                if (kg+3 < K) av.w = Arow[kg+3];
            }
        }
        if (wok){
            if (kg+4 <= K) wv = *(const float4*)(Wrow + kg);
            else {
                if (kg   < K) wv.x = Wrow[kg];
                if (kg+1 < K) wv.y = Wrow[kg+1];
                if (kg+2 < K) wv.z = Wrow[kg+2];
                if (kg+3 < K) wv.w = Wrow[kg+3];
            }
        }
        __syncthreads();
        As [ldk4+0][ldr]=av.x; As [ldk4+1][ldr]=av.y; As [ldk4+2][ldr]=av.z; As [ldk4+3][ldr]=av.w;
        Ws1[ldk4+0][ldr]=wv.x; Ws1[ldk4+1][ldr]=wv.y; Ws1[ldk4+2][ldr]=wv.z; Ws1[ldk4+3][ldr]=wv.w;
        __syncthreads();
        #pragma unroll
        for (int k=0;k<16;k++){
            const float4 a  = *(const float4*)&As[k][ty<<2];
            const float4 b1 = *(const float4*)&Ws1[k][tx<<2];
            float ar[4] = {a.x,a.y,a.z,a.w};
            float br[4] = {b1.x,b1.y,b1.z,b1.w};
            #pragma unroll
            for (int i=0;i<4;i++)
                #pragma unroll
                for (int j=0;j<4;j++)
                    acc[i][j] = fmaf(ar[i], br[j], acc[i][j]);
        }
    }

    int c0 = col0 + (tx<<2);
    if (c0 >= N) return;
    bool full = (c0+4 <= N);
    float bb1[4] = {0,0,0,0};
    if (EPI==5){
        if (full){ float4 bz = *(const float4*)&bias[c0]; bb1[0]=bz.x; bb1[1]=bz.y; bb1[2]=bz.z; bb1[3]=bz.w; }
        else { for (int j=0;j<4;j++) if (c0+j<N) bb1[j]=bias[c0+j]; }
    }
    #pragma unroll
    for (int i=0;i<4;i++){
        int r = row0 + (ty<<2) + i;
        if (r >= M) continue;
        float o[4];
        #pragma unroll
        for (int j=0;j<4;j++){
            float v = acc[i][j];
            if (EPI==5){ float t = v + bb1[j]; v = (t > 20.f) ? t : log1pf(__expf(t)); }
            o[j] = v;
        }
        size_t off = (size_t)r*N + c0;
        if (full){ float4 ov = {o[0],o[1],o[2],o[3]}; *(float4*)&C[off] = ov; }
        else { for (int j=0;j<4;j++) if (c0+j<N) C[off+j]=o[j]; }
    }
}

// ---------------- MFMA bf16 GEMM: C(M,N) = A(M,K)bf16 * W(N,K)^T ----------------
// BM=64, BN=128, BK=64, 4 waves (2M x 2N), wave tile 32x64 (2x4 frags of 16x16x32)
// EPI: 0 plain f32 | 1 +bias f32 | 2 +resid f32 | 3 +resid+bias f32 | 4 dual silu(a1+b1)*(a2+b2) -> bf16
__device__ __forceinline__ int swz(int row, int chunk){
    return (row << 7) + (((chunk ^ (row & 7))) << 4);
}

template<int EPI, bool WB>
__global__ __launch_bounds__(256) void mgemm_k(
    const u16* __restrict__ A,
    const void* __restrict__ W1v, const void* __restrict__ W2v,
    const float* __restrict__ bias1, const float* __restrict__ bias2,
    float* __restrict__ Cf, u16* __restrict__ Cb,
    int M, int N, int K)
{
    constexpr int SMB = (EPI==4) ? 40960 : 24576;
    __shared__ __attribute__((aligned(16))) char sm[SMB];
    char* sA  = sm;          // 8KB : 64 x 64 bf16 (swizzled)
    char* sB  = sm + 8192;   // 16KB: 128 x 64 bf16
    char* sB2 = sm + 24576;  // 16KB (EPI==4)

    const int tid = threadIdx.x;
    const int row0 = blockIdx.y << 6;
    const int col0 = blockIdx.x << 7;
    const int w = tid >> 6, lane = tid & 63;
    const int wm = w & 1, wn = w >> 1;
    const int lr = lane & 15, lk = lane >> 4;

    f32x4 acc[2][4] = {};
    f32x4 acc2[2][4] = {};

    const u16*   W1b = (const u16*)W1v;
    const u16*   W2b = (const u16*)W2v;
    const float* W1f = (const float*)W1v;
    const float* W2f = (const float*)W2v;

    const int ar0 = tid >> 3;   // 0..31
    const int ac8 = tid & 7;    // chunk (8 bf16)
    const int nkt = K >> 6;

    for (int kt = 0; kt < nkt; kt++){
        const int kb = kt << 6;
        // ---- issue global loads (before barrier: latency hides under prior compute)
        s16x8 aval[2];
        #pragma unroll
        for (int i=0;i<2;i++){
            int row = i*32 + ar0;
            int gr = row0 + row;
            if (gr < M) aval[i] = *(const s16x8*)(A + (size_t)gr*K + kb + ac8*8);
            else        aval[i] = s16x8{0,0,0,0,0,0,0,0};
        }
        s16x8 bval[4]; s16x8 b2val[4];
        float4 bvf[8]; float4 b2vf[8];
        if (WB){
            #pragma unroll
            for (int i=0;i<4;i++){
                int row = i*32 + ar0;
                bval[i] = *(const s16x8*)(W1b + (size_t)(col0+row)*K + kb + ac8*8);
            }
            if (EPI==4){
                #pragma unroll
                for (int i=0;i<4;i++){
                    int row = i*32 + ar0;
                    b2val[i] = *(const s16x8*)(W2b + (size_t)(col0+row)*K + kb + ac8*8);
                }
            }
        } else {
            #pragma unroll
            for (int i=0;i<8;i++){
                int s = i*256 + tid;
                int row = s >> 4, q = s & 15;
                bvf[i] = *(const float4*)(W1f + (size_t)(col0+row)*K + kb + q*4);
            }
            if (EPI==4){
                #pragma unroll
                for (int i=0;i<8;i++){
                    int s = i*256 + tid;
                    int row = s >> 4, q = s & 15;
                    b2vf[i] = *(const float4*)(W2f + (size_t)(col0+row)*K + kb + q*4);
                }
            }
        }
        __syncthreads();   // previous compute done; safe to overwrite LDS
        #pragma unroll
        for (int i=0;i<2;i++){
            int row = i*32 + ar0;
            *(s16x8*)(sA + swz(row, ac8)) = aval[i];
        }
        if (WB){
            #pragma unroll
            for (int i=0;i<4;i++){
                int row = i*32 + ar0;
                *(s16x8*)(sB + swz(row, ac8)) = bval[i];
            }
            if (EPI==4){
                #pragma unroll
                for (int i=0;i<4;i++){
                    int row = i*32 + ar0;
                    *(s16x8*)(sB2 + swz(row, ac8)) = b2val[i];
                }
            }
        } else {
            #pragma unroll
            for (int i=0;i<8;i++){
                int s = i*256 + tid;
                int row = s >> 4, q = s & 15;
                float4 v = bvf[i];
                s16x4 cv = { (short)f2bf(v.x), (short)f2bf(v.y), (short)f2bf(v.z), (short)f2bf(v.w) };
                int off = (row << 7) + (((q >> 1) ^ (row & 7)) << 4) + ((q & 1) << 3);
                *(s16x4*)(sB + off) = cv;
            }
            if (EPI==4){
                #pragma unroll
                for (int i=0;i<8;i++){
                    int s = i*256 + tid;
                    int row = s >> 4, q = s & 15;
                    float4 v = b2vf[i];
                    s16x4 cv = { (short)f2bf(v.x), (short)f2bf(v.y), (short)f2bf(v.z), (short)f2bf(v.w) };
                    int off = (row << 7) + (((q >> 1) ^ (row & 7)) << 4) + ((q & 1) << 3);
                    *(s16x4*)(sB2 + off) = cv;
                }
            }
        }
        __syncthreads();   // LDS tile visible
        #pragma unroll
        for (int ks=0; ks<2; ks++){
            s16x8 af[2], bfr[4];
            #pragma unroll
            for (int m=0;m<2;m++)
                af[m] = *(const s16x8*)(sA + swz(wm*32 + m*16 + lr, lk + ks*4));
            #pragma unroll
            for (int n=0;n<4;n++)
                bfr[n] = *(const s16x8*)(sB + swz(wn*64 + n*16 + lr, lk + ks*4));
            #pragma unroll
            for (int m=0;m<2;m++)
                #pragma unroll
                for (int n=0;n<4;n++)
                    acc[m][n] = mfma_bf16(af[m], bfr[n], acc[m][n]);
            if (EPI==4){
                s16x8 b2r[4];
                #pragma unroll
                for (int n=0;n<4;n++)
                    b2r[n] = *(const s16x8*)(sB2 + swz(wn*64 + n*16 + lr, lk + ks*4));
                #pragma unroll
                for (int m=0;m<2;m++)
                    #pragma unroll
                    for (int n=0;n<4;n++)
                        acc2[m][n] = mfma_bf16(af[m], b2r[n], acc2[m][n]);
            }
        }
    }

    // ---- epilogue: C row = row0 + wm*32 + m*16 + lk*4 + r ; col = col0 + wn*64 + n*16 + lr
    #pragma unroll
    for (int n=0;n<4;n++){
        int gc = col0 + wn*64 + n*16 + lr;
        float b1 = 0.f, b2 = 0.f;
        if (EPI==1||EPI==3||EPI==4) b1 = bias1[gc];
        if (EPI==4) b2 = bias2[gc];
        #pragma unroll
        for (int m=0;m<2;m++){
            #pragma unroll
            for (int r=0;r<4;r++){
                int gr = row0 + wm*32 + m*16 + lk*4 + r;
                if (gr >= M) continue;
                float v = acc[m][n][r];
                if (EPI==1||EPI==3) v += b1;
                if (EPI==2||EPI==3) v += Cf[(size_t)gr*N + gc];
                if (EPI==4){
                    float v1 = v + b1;
                    float v2 = acc2[m][n][r] + b2;
                    float o = v1 * sigmoidf_(v1) * v2;
                    Cb[(size_t)gr*N + gc] = f2bf(o);
                } else {
                    Cf[(size_t)gr*N + gc] = v;
                }
            }
        }
    }
}

// ---------------- fp32 -> bf16 weight conversion ----------------
__global__ void cvtw_k(const float* __restrict__ s, u16* __restrict__ d, int n)
{
    int i = blockIdx.x*blockDim.x + threadIdx.x;
    int idx = i*4;
    if (idx + 4 <= n){
        float4 v = *(const float4*)(s + idx);
        s16x4 cv = { (short)f2bf(v.x), (short)f2bf(v.y), (short)f2bf(v.z), (short)f2bf(v.w) };
        *(s16x4*)(d + idx) = cv;
    } else {
        for (int j=idx;j<n;j++) d[j] = f2bf(s[j]);
    }
}

// ---------------- Scan phase A ----------------
__global__ __launch_bounds__(384) void scanA_k(
    const float* __restrict__ dt, const float* __restrict__ xa,
    const float* __restrict__ dbc, const float* __restrict__ a_log,
    float* __restrict__ Pout, float* __restrict__ Sout)
{
    int b = blockIdx.x / NCH;
    int c = blockIdx.x % NCH;
    int d = threadIdx.x;
    __shared__ float Bs[CHL][NST];
    for (int t = threadIdx.x; t < CHL*NST; t += 384){
        int j = t >> 4, n = t & 15;
        Bs[j][n] = dbc[(size_t)(b*LL + c*CHL + j)*56 + 24 + n];
    }
    __syncthreads();
    float Aa[NST];
    #pragma unroll
    for (int n=0;n<NST;n++) Aa[n] = -__expf(a_log[d*NST+n]);
    float hst[NST], P[NST];
    #pragma unroll
    for (int n=0;n<NST;n++){ hst[n]=0.f; P[n]=1.f; }
    for (int j=0;j<CHL;j++){
        int row = b*LL + c*CHL + j;
        float dtv = dt[(size_t)row*DD + d];
        float xv  = xa[(size_t)row*DD + d];
        float du = dtv*xv;
        #pragma unroll
        for (int n=0;n<NST;n++){
            float e = __expf(dtv*Aa[n]);
            hst[n] = fmaf(hst[n], e, du*Bs[j][n]);
            P[n] *= e;
        }
    }
    size_t base = ((size_t)(b*NCH + c)*DD + d)*NST;
    #pragma unroll
    for (int n=0;n<NST;n++){ Pout[base+n]=P[n]; Sout[base+n]=hst[n]; }
}

// ---------------- Scan phase B ----------------
__global__ void scanB_k(const float* __restrict__ P, const float* __restrict__ S,
                        float* __restrict__ Hin)
{
    int idx = blockIdx.x*blockDim.x + threadIdx.x;
    if (idx >= BB*DD) return;
    int b = idx / DD, d = idx % DD;
    float h[NST];
    #pragma unroll
    for (int n=0;n<NST;n++) h[n]=0.f;
    for (int c=0;c<NCH;c++){
        size_t base = ((size_t)(b*NCH + c)*DD + d)*NST;
        #pragma unroll
        for (int n=0;n<NST;n++){
            Hin[base+n] = h[n];
            h[n] = fmaf(P[base+n], h[n], S[base+n]);
        }
    }
}

// ---------------- Scan phase C: replay + D_skip + SiLU(z) gate -> bf16 yg ----------------
__global__ __launch_bounds__(384) void scanC_k(
    const float* __restrict__ dt, const float* __restrict__ xa,
    const float* __restrict__ dbc, const float* __restrict__ a_log,
    const float* __restrict__ Hin, const float* __restrict__ xz,
    const float* __restrict__ dskip, u16* __restrict__ yg)
{
    int b = blockIdx.x / NCH;
    int c = blockIdx.x % NCH;
    int d = threadIdx.x;
    __shared__ float Bs[CHL][NST], Cs[CHL][NST];
    for (int t = threadIdx.x; t < CHL*NST*2; t += 384){
        int which = t / (CHL*NST);
        int u = t % (CHL*NST);
        int j = u >> 4, n = u & 15;
        float v = dbc[(size_t)(b*LL + c*CHL + j)*56 + 24 + which*NST + n];
        if (which==0) Bs[j][n]=v; else Cs[j][n]=v;
    }
    __syncthreads();
    float Aa[NST];
    #pragma unroll
    for (int n=0;n<NST;n++) Aa[n] = -__expf(a_log[d*NST+n]);
    float hst[NST];
    size_t hb = ((size_t)(b*NCH + c)*DD + d)*NST;
    #pragma unroll
    for (int n=0;n<NST;n++) hst[n] = Hin[hb+n];
    float dsk = dskip[d];
    for (int j=0;j<CHL;j++){
        int row = b*LL + c*CHL + j;
        float dtv = dt[(size_t)row*DD + d];
        float xv  = xa[(size_t)row*DD + d];
        float du = dtv*xv;
        float y = 0.f;
        #pragma unroll
        for (int n=0;n<NST;n++){
            float e = __expf(dtv*Aa[n]);
            hst[n] = fmaf(hst[n], e, du*Bs[j][n]);
            y = fmaf(hst[n], Cs[j][n], y);
        }
        float zv = xz[(size_t)row*768 + 384 + d];
        float g = zv * sigmoidf_(zv);
        yg[(size_t)row*DD + d] = f2bf((y + dsk*xv)*g);
    }
}

// ---------------- host-side MFMA launcher (WB gating) ----------------
template<int EPI>
static void mg(bool wb, dim3 g, hipStream_t s, const void* A,
               const void* Wb, const void* Wf, const void* W2b, const void* W2f,
               const float* b1, const float* b2, float* Cf, u16* Cb,
               int M, int N, int K)
{
    if (wb) mgemm_k<EPI,true ><<<g,256,0,s>>>((const u16*)A, Wb, W2b, b1, b2, Cf, Cb, M, N, K);
    else    mgemm_k<EPI,false><<<g,256,0,s>>>((const u16*)A, Wf, W2f, b1, b2, Cf, Cb, M, N, K);
}

extern "C" void kernel_launch(void* const* d_in, const int* in_sizes, int n_in,
                              void* d_out, int out_size, void* d_ws, size_t ws_size,
                              hipStream_t stream)
{
    const float* x         = (const float*)d_in[0];
    const float* patch_w   = (const float*)d_in[1];
    const float* patch_b   = (const float*)d_in[2];
    const float* norm1_w   = (const float*)d_in[3];
    const float* norm1_b   = (const float*)d_in[4];
    const float* in_proj_w = (const float*)d_in[5];
    const float* conv_w    = (const float*)d_in[6];
    const float* conv_b    = (const float*)d_in[7];
    const float* x_proj_w  = (const float*)d_in[8];
    const float* dt_w      = (const float*)d_in[9];
    const float* dt_b      = (const float*)d_in[10];
    const float* A_log     = (const float*)d_in[11];
    const float* D_skip    = (const float*)d_in[12];
    const float* out_w     = (const float*)d_in[13];
    const float* norm2_w   = (const float*)d_in[14];
    const float* norm2_b   = (const float*)d_in[15];
    const float* w1_w      = (const float*)d_in[16];
    const float* w1_b      = (const float*)d_in[17];
    const float* w2_w      = (const float*)d_in[18];
    const float* w2_b      = (const float*)d_in[19];
    const float* w3_w      = (const float*)d_in[20];
    const float* w3_b      = (const float*)d_in[21];
    const float* normf_w   = (const float*)d_in[22];
    const float* normf_b   = (const float*)d_in[23];

    char* wsb = (char*)d_ws;
    size_t o = 0;
    auto take = [&](size_t bytes) -> char* {
        char* p = wsb + o;
        o += (bytes + 255) & ~(size_t)255;
        return p;
    };

    float* h    = (float*)take((size_t)602112*4);
    float* xz   = (float*)take((size_t)1204224*4);
    float* xa   = (float*)take((size_t)602112*4);
    float* dbc  = (float*)take((size_t)87808*4);
    float* dtb_ = (float*)take((size_t)602112*4);
    float* Pb   = (float*)take((size_t)688128*4);
    float* Sb   = (float*)take((size_t)688128*4);
    float* Hi   = (float*)take((size_t)688128*4);
    u16*  xn    = (u16*)take((size_t)602112*2);
    u16*  yg    = (u16*)take((size_t)602112*2);
    u16*  hid   = (u16*)take((size_t)1605632*2);
    u16*  patches = hid;   // alias: needs 1204224 u16 <= 1605632, consumed before hid produced

    const size_t NPW = 294912, NIN = 7077888, NOUT = 3538944, NW1 = 9437184, NW2 = 9437184, NW3 = 9437184;
    u16* wcP = (u16*)take(NPW*2);
    u16* wcI = (u16*)take(NIN*2);
    u16* wcO = (u16*)take(NOUT*2);
    u16* wc1 = (u16*)take(NW1*2);
    u16* wc2 = (u16*)take(NW2*2);
    u16* wc3 = (u16*)take(NW3*2);
    bool wb = (ws_size >= o);

    if (wb){
        cvtw_k<<<(int)((NPW/4+255)/256), 256, 0, stream>>>(patch_w, wcP, (int)NPW);
        cvtw_k<<<(int)((NIN/4+255)/256), 256, 0, stream>>>(in_proj_w, wcI, (int)NIN);
        cvtw_k<<<(int)((NOUT/4+255)/256),256, 0, stream>>>(out_w, wcO, (int)NOUT);
        cvtw_k<<<(int)((NW1/4+255)/256), 256, 0, stream>>>(w1_w, wc1, (int)NW1);
        cvtw_k<<<(int)((NW2/4+255)/256), 256, 0, stream>>>(w2_w, wc2, (int)NW2);
        cvtw_k<<<(int)((NW3/4+255)/256), 256, 0, stream>>>(w3_w, wc3, (int)NW3);
    }

    const int GY = (MROWS + 63)/64;   // 25

    // Patch embedding: h = patches @ patch_w^T + patch_b
    gather_k<<<(MROWS*768+255)/256, 256, 0, stream>>>(x, patches);
    mg<1>(wb, dim3(3,GY), stream, patches, wcP, patch_w, nullptr, nullptr,
          patch_b, nullptr, h, nullptr, MROWS, DD, 768);

    for (int i=0;i<NDEPTH;i++){
        ln_k<1><<<MROWS, 64, 0, stream>>>(h, norm1_w + i*DD, norm1_b + i*DD, xn);
        mg<0>(wb, dim3(6,GY), stream, xn, wcI + (size_t)i*768*DD, in_proj_w + (size_t)i*768*DD,
              nullptr, nullptr, nullptr, nullptr, xz, nullptr, MROWS, 768, DD);
        conv_silu_k<<<(MROWS*DD+255)/256, 256, 0, stream>>>(xz, conv_w + i*DD*4, conv_b + i*DD, xa);
        gemm_k<0><<<dim3(1,GY), 256, 0, stream>>>(xa, DD, x_proj_w + (size_t)i*56*DD,
                                                  nullptr, dbc, MROWS, 56, DD);
        gemm_k<5><<<dim3(6,GY), 256, 0, stream>>>(dbc, 56, dt_w + (size_t)i*DD*RRANK, dt_b + i*DD,
                                                  dtb_, MROWS, DD, RRANK);
        scanA_k<<<BB*NCH, DD, 0, stream>>>(dtb_, xa, dbc, A_log + (size_t)i*DD*NST, Pb, Sb);
        scanB_k<<<(BB*DD+255)/256, 256, 0, stream>>>(Pb, Sb, Hi);
        scanC_k<<<BB*NCH, DD, 0, stream>>>(dtb_, xa, dbc, A_log + (size_t)i*DD*NST,
                                           Hi, xz, D_skip + i*DD, yg);
        mg<2>(wb, dim3(3,GY), stream, yg, wcO + (size_t)i*DD*DD, out_w + (size_t)i*DD*DD,
              nullptr, nullptr, nullptr, nullptr, h, nullptr, MROWS, DD, DD);
        ln_k<1><<<MROWS, 64, 0, stream>>>(h, norm2_w + i*DD, norm2_b + i*DD, xn);
        mg<4>(wb, dim3(8,GY), stream, xn,
              wc1 + (size_t)i*HHID*DD, w1_w + (size_t)i*HHID*DD,
              wc2 + (size_t)i*HHID*DD, w2_w + (size_t)i*HHID*DD,
              w1_b + i*HHID, w2_b + i*HHID, nullptr, hid, MROWS, HHID, DD);
        mg<3>(wb, dim3(3,GY), stream, hid, wc3 + (size_t)i*DD*HHID, w3_w + (size_t)i*DD*HHID,
              nullptr, nullptr, w3_b + i*DD, nullptr, h, nullptr, MROWS, DD, HHID);
    }

    ln_k<0><<<MROWS, 64, 0, stream>>>(h, normf_w, normf_b, d_out);
}